// Round 1
// baseline (238.178 us; speedup 1.0000x reference)
//
#include <hip/hip_runtime.h>
#include <cstdint>
#include <cstddef>

// B=2, L=2048, E=1024, H=16, D=64
#define BB 2
#define LL 2048
#define EE 1024
#define HH 16
#define DD 64
#define MM (BB*LL)

typedef short short8 __attribute__((ext_vector_type(8)));
typedef float f32x4 __attribute__((ext_vector_type(4)));

__device__ __forceinline__ unsigned short f32_bf16(float f) {
  union { float f; unsigned u; } c; c.f = f;
  c.u += 0x7fffu + ((c.u >> 16) & 1u);
  return (unsigned short)(c.u >> 16);
}

// ---------------- fp32 -> bf16 conversion ----------------
__global__ void cvt_kernel(const float* __restrict__ src, unsigned short* __restrict__ dst, int n) {
  int i = (blockIdx.x * 256 + threadIdx.x) * 4;
  if (i >= n) return;
  float4 v = *(const float4*)(src + i);
  union { unsigned short s[4]; uint2 u; } o;
  o.s[0] = f32_bf16(v.x); o.s[1] = f32_bf16(v.y);
  o.s[2] = f32_bf16(v.z); o.s[3] = f32_bf16(v.w);
  *(uint2*)(dst + i) = o.u;
}

// ---------------- 128x128 bf16 GEMM (NT: A MxK, W NxK), m97-style ----------------
// MODE 0: QKV projection. z selects Wq/Wk/Wv; out scatter to (B,H,L,D) bf16,
//         multiply by mask[m], and z==0 additionally by 1/sqrt(D).
// MODE 1: out = A @ W0^T + bias, fp32 row-major out.
template<int MODE>
__global__ __launch_bounds__(256, 2)
void gemm128(const unsigned short* __restrict__ A,
             const unsigned short* __restrict__ W0,
             const unsigned short* __restrict__ W1,
             const unsigned short* __restrict__ W2,
             const float* __restrict__ mask,
             const float* __restrict__ bias,
             unsigned short* __restrict__ O0,
             unsigned short* __restrict__ O1,
             unsigned short* __restrict__ O2,
             float* __restrict__ OF)
{
  constexpr int K = EE;
  const int tid = threadIdx.x;
  const int lane = tid & 63;
  const int wid = tid >> 6;
  const int g = lane >> 4, li = lane & 15;
  const int m0 = blockIdx.y * 128;
  const int n0 = blockIdx.x * 128;
  const int z = blockIdx.z;

  const unsigned short* Wp = W0;
  if (MODE == 0) Wp = (z == 0) ? W0 : ((z == 1) ? W1 : W2);

  __shared__ unsigned short As[128 * 64];
  __shared__ unsigned short Bs[128 * 64];

  f32x4 acc[4][4];
  f32x4 zero = {0.f, 0.f, 0.f, 0.f};
  #pragma unroll
  for (int i = 0; i < 4; ++i)
    #pragma unroll
    for (int j = 0; j < 4; ++j) acc[i][j] = zero;

  const int wm = (wid >> 1) * 64;
  const int wn = (wid & 1) * 64;

  for (int kt = 0; kt < K; kt += 64) {
    // stage A,B tiles: global_load_lds 16B, linear LDS dest, pre-swizzled global src
    #pragma unroll
    for (int j = 0; j < 4; ++j) {
      int c = j * 256 + tid;                 // 16B chunk id, 0..1023
      int row = c >> 3;                      // 0..127
      int lcol = ((c & 7) * 16) ^ ((row & 7) << 4);  // logical byte col (inverse swizzle)
      __builtin_amdgcn_global_load_lds(
        (const __attribute__((address_space(1))) void*)((const char*)(A + (size_t)(m0 + row) * K + kt) + lcol),
        (__attribute__((address_space(3))) void*)((char*)As + c * 16), 16, 0, 0);
      __builtin_amdgcn_global_load_lds(
        (const __attribute__((address_space(1))) void*)((const char*)(Wp + (size_t)(n0 + row) * K + kt) + lcol),
        (__attribute__((address_space(3))) void*)((char*)Bs + c * 16), 16, 0, 0);
    }
    __syncthreads();

    #pragma unroll
    for (int kk = 0; kk < 2; ++kk) {
      short8 a[4], b[4];
      const int colb = (kk * 32 + g * 8) * 2;
      #pragma unroll
      for (int i = 0; i < 4; ++i) {
        int ar = wm + i * 16 + li;
        a[i] = *(const short8*)((const char*)As + ar * 128 + (colb ^ ((ar & 7) << 4)));
        int br = wn + i * 16 + li;
        b[i] = *(const short8*)((const char*)Bs + br * 128 + (colb ^ ((br & 7) << 4)));
      }
      #pragma unroll
      for (int i = 0; i < 4; ++i)
        #pragma unroll
        for (int j = 0; j < 4; ++j)
          acc[i][j] = __builtin_amdgcn_mfma_f32_16x16x32_bf16(a[i], b[j], acc[i][j], 0, 0, 0);
    }
    __syncthreads();
  }

  // epilogue. C/D layout: col = li, row = g*4 + r
  if (MODE == 0) {
    unsigned short* Op = (z == 0) ? O0 : ((z == 1) ? O1 : O2);
    const float sc = (z == 0) ? 0.125f : 1.0f;  // 1/sqrt(64) folded into Q
    #pragma unroll
    for (int i = 0; i < 4; ++i) {
      #pragma unroll
      for (int r = 0; r < 4; ++r) {
        int m = m0 + wm + i * 16 + g * 4 + r;
        float mk = mask[m] * sc;
        int bb = m >> 11;          // / 2048
        int l  = m & (LL - 1);
        #pragma unroll
        for (int j = 0; j < 4; ++j) {
          int n = n0 + wn + j * 16 + li;
          int h = n >> 6, d = n & 63;
          size_t off = (((size_t)(bb * HH + h)) * LL + l) * DD + d;
          Op[off] = f32_bf16(acc[i][j][r] * mk);
        }
      }
    }
  } else {
    #pragma unroll
    for (int i = 0; i < 4; ++i) {
      #pragma unroll
      for (int j = 0; j < 4; ++j) {
        int n = n0 + wn + j * 16 + li;
        float bv = bias[n];
        #pragma unroll
        for (int r = 0; r < 4; ++r) {
          int m = m0 + wm + i * 16 + g * 4 + r;
          OF[(size_t)m * EE + n] = acc[i][j][r] + bv;
        }
      }
    }
  }
}

// ---------------- causal flash attention ----------------
// Q,K,V: (B,H,L,D) bf16; Q pre-scaled by 1/sqrt(D); mask pre-applied.
// Y out: (B,L,E) bf16. Block: 4 waves x 16 q-rows (QBLK=64), KVBLK=64.
__global__ __launch_bounds__(256, 2)
void attn_kernel(const unsigned short* __restrict__ Q,
                 const unsigned short* __restrict__ Kt,
                 const unsigned short* __restrict__ V,
                 unsigned short* __restrict__ Y)
{
  const int tid = threadIdx.x, lane = tid & 63, w = tid >> 6;
  const int g = lane >> 4, li = lane & 15;
  const int qt = blockIdx.x;
  const int bh = blockIdx.y;
  const int b = bh >> 4, h = bh & (HH - 1);
  const int q0 = qt * 64;
  const size_t base = (size_t)bh * LL * DD;

  __shared__ unsigned short Ks[64 * 64];
  __shared__ unsigned short Vt[64 * 64];
  __shared__ unsigned short Pl[4][16 * 64];

  // Q A-fragments, straight from global (16B per lane)
  short8 aq[2];
  #pragma unroll
  for (int kk = 0; kk < 2; ++kk)
    aq[kk] = *(const short8*)(Q + base + (size_t)(q0 + w * 16 + li) * DD + kk * 32 + g * 8);

  f32x4 o[4];
  f32x4 zero = {0.f, 0.f, 0.f, 0.f};
  #pragma unroll
  for (int i = 0; i < 4; ++i) o[i] = zero;
  float mrun[4], lrun[4];
  #pragma unroll
  for (int r = 0; r < 4; ++r) { mrun[r] = -INFINITY; lrun[r] = 0.f; }

  const int nt = qt + 1;
  for (int t = 0; t < nt; ++t) {
    const int kv0 = t * 64;
    // stage K tile [kv][d] via global_load_lds, swizzled
    #pragma unroll
    for (int jj = 0; jj < 2; ++jj) {
      int c = jj * 256 + tid;
      int row = c >> 3;
      int lcol = ((c & 7) * 16) ^ ((row & 7) << 4);
      __builtin_amdgcn_global_load_lds(
        (const __attribute__((address_space(1))) void*)((const char*)(Kt + base + (size_t)(kv0 + row) * DD) + lcol),
        (__attribute__((address_space(3))) void*)((char*)Ks + c * 16), 16, 0, 0);
    }
    // stage V transposed: Vt[d][kv], swizzled (scalar writes)
    #pragma unroll
    for (int jj = 0; jj < 2; ++jj) {
      int c = jj * 256 + tid;
      int kv = c >> 3;
      int d0 = (c & 7) * 8;
      short8 vv = *(const short8*)(V + base + (size_t)(kv0 + kv) * DD + d0);
      #pragma unroll
      for (int e = 0; e < 8; ++e) {
        int d = d0 + e;
        Vt[d * 64 + (kv ^ ((d & 7) << 3))] = (unsigned short)vv[e];
      }
    }
    __syncthreads();

    // S = Q K^T  (s[ni]: 16 q-rows x 16 kv-cols)
    f32x4 s[4];
    #pragma unroll
    for (int i = 0; i < 4; ++i) s[i] = zero;
    #pragma unroll
    for (int kk = 0; kk < 2; ++kk) {
      const int colb = (kk * 32 + g * 8) * 2;
      #pragma unroll
      for (int ni = 0; ni < 4; ++ni) {
        int kr = ni * 16 + li;
        short8 bk = *(const short8*)((const char*)Ks + kr * 128 + (colb ^ ((kr & 7) << 4)));
        s[ni] = __builtin_amdgcn_mfma_f32_16x16x32_bf16(aq[kk], bk, s[ni], 0, 0, 0);
      }
    }

    // causal mask on the diagonal tile (kv0 == q0 there)
    if (t == nt - 1) {
      #pragma unroll
      for (int ni = 0; ni < 4; ++ni)
        #pragma unroll
        for (int r = 0; r < 4; ++r) {
          int qrow = w * 16 + g * 4 + r;
          int krow = ni * 16 + li;
          if (krow > qrow) s[ni][r] = -INFINITY;
        }
    }

    // online softmax (rows live in 16-lane groups)
    float alpha[4];
    unsigned short pb[4][4];
    #pragma unroll
    for (int r = 0; r < 4; ++r) {
      float mv = fmaxf(fmaxf(s[0][r], s[1][r]), fmaxf(s[2][r], s[3][r]));
      #pragma unroll
      for (int x = 1; x < 16; x <<= 1) mv = fmaxf(mv, __shfl_xor(mv, x, 64));
      float mnew = fmaxf(mrun[r], mv);
      alpha[r] = __expf(mrun[r] - mnew);
      mrun[r] = mnew;
      float rs = 0.f;
      #pragma unroll
      for (int ni = 0; ni < 4; ++ni) {
        float p = __expf(s[ni][r] - mnew);
        rs += p;
        pb[ni][r] = f32_bf16(p);
      }
      #pragma unroll
      for (int x = 1; x < 16; x <<= 1) rs += __shfl_xor(rs, x, 64);
      lrun[r] = lrun[r] * alpha[r] + rs;
      #pragma unroll
      for (int nd = 0; nd < 4; ++nd) o[nd][r] *= alpha[r];
    }

    // P -> LDS (C-layout write, swizzled), then read back in A-layout
    #pragma unroll
    for (int ni = 0; ni < 4; ++ni)
      #pragma unroll
      for (int r = 0; r < 4; ++r) {
        int row = g * 4 + r;
        int col = ni * 16 + li;
        Pl[w][row * 64 + (col ^ ((row & 7) << 3))] = pb[ni][r];
      }
    __syncthreads();

    short8 pa[2];
    #pragma unroll
    for (int kk = 0; kk < 2; ++kk) {
      const int colb = (kk * 32 + g * 8) * 2;
      pa[kk] = *(const short8*)((const char*)&Pl[w][0] + li * 128 + (colb ^ ((li & 7) << 4)));
    }
    #pragma unroll
    for (int kk = 0; kk < 2; ++kk) {
      const int colb = (kk * 32 + g * 8) * 2;
      #pragma unroll
      for (int nd = 0; nd < 4; ++nd) {
        int vr = nd * 16 + li;
        short8 bv = *(const short8*)((const char*)Vt + vr * 128 + (colb ^ ((vr & 7) << 4)));
        o[nd] = __builtin_amdgcn_mfma_f32_16x16x32_bf16(pa[kk], bv, o[nd], 0, 0, 0);
      }
    }
    __syncthreads();
  }

  // epilogue: normalize and write Y (B,L,E) bf16
  #pragma unroll
  for (int r = 0; r < 4; ++r) {
    float inv = 1.0f / lrun[r];
    int qrow = q0 + w * 16 + g * 4 + r;
    size_t rowoff = ((size_t)b * LL + qrow) * EE + h * DD;
    #pragma unroll
    for (int nd = 0; nd < 4; ++nd)
      Y[rowoff + nd * 16 + li] = f32_bf16(o[nd][r] * inv);
  }
}

// ---------------- launch ----------------
extern "C" void kernel_launch(void* const* d_in, const int* in_sizes, int n_in,
                              void* d_out, int out_size, void* d_ws, size_t ws_size,
                              hipStream_t stream) {
  const float* x    = (const float*)d_in[0];
  const float* mask = (const float*)d_in[1];
  const float* Wq   = (const float*)d_in[2];
  const float* Wk   = (const float*)d_in[3];
  const float* Wv   = (const float*)d_in[4];
  const float* Wo   = (const float*)d_in[5];
  const float* bo   = (const float*)d_in[6];
  float* out = (float*)d_out;

  char* ws = (char*)d_ws;
  unsigned short* xb  = (unsigned short*)(ws);                         // 8 MiB
  unsigned short* wqb = (unsigned short*)(ws + ((size_t)8  << 20));    // 2 MiB
  unsigned short* wkb = (unsigned short*)(ws + ((size_t)10 << 20));
  unsigned short* wvb = (unsigned short*)(ws + ((size_t)12 << 20));
  unsigned short* wob = (unsigned short*)(ws + ((size_t)14 << 20));
  unsigned short* Qb  = (unsigned short*)(ws + ((size_t)16 << 20));    // 8 MiB
  unsigned short* Kb  = (unsigned short*)(ws + ((size_t)24 << 20));
  unsigned short* Vb  = (unsigned short*)(ws + ((size_t)32 << 20));
  unsigned short* Yb  = (unsigned short*)(ws + ((size_t)40 << 20));

  cvt_kernel<<<4096, 256, 0, stream>>>(x,  xb,  MM * EE);
  cvt_kernel<<<1024, 256, 0, stream>>>(Wq, wqb, EE * EE);
  cvt_kernel<<<1024, 256, 0, stream>>>(Wk, wkb, EE * EE);
  cvt_kernel<<<1024, 256, 0, stream>>>(Wv, wvb, EE * EE);
  cvt_kernel<<<1024, 256, 0, stream>>>(Wo, wob, EE * EE);

  gemm128<0><<<dim3(EE / 128, MM / 128, 3), 256, 0, stream>>>(
      xb, wqb, wkb, wvb, mask, nullptr, Qb, Kb, Vb, nullptr);

  attn_kernel<<<dim3(LL / 64, BB * HH), 256, 0, stream>>>(Qb, Kb, Vb, Yb);

  gemm128<1><<<dim3(EE / 128, MM / 128, 1), 256, 0, stream>>>(
      Yb, wob, nullptr, nullptr, nullptr, bo, nullptr, nullptr, nullptr, out);
}

// Round 3
// 121.930 us; speedup vs baseline: 1.9534x; 1.9534x over previous
//
#include <hip/hip_runtime.h>
#include <cstdint>
#include <cstddef>
#include <math.h>

// B=2, L=2048, E=1024, H=16, D=64
#define BB 2
#define LL 2048
#define EE 1024
#define HH 16
#define DD 64
#define MM (BB*LL)

typedef short short8 __attribute__((ext_vector_type(8)));
typedef float f32x4 __attribute__((ext_vector_type(4)));
typedef float f32x16 __attribute__((ext_vector_type(16)));

#define GPTR __attribute__((address_space(1)))
#define LPTR __attribute__((address_space(3)))

__device__ __forceinline__ unsigned short f32_bf16(float f) {
  union { float f; unsigned u; } c; c.f = f;
  c.u += 0x7fffu + ((c.u >> 16) & 1u);
  return (unsigned short)(c.u >> 16);
}

// pack 2 f32 -> 2 bf16 in one VALU op
__device__ __forceinline__ unsigned pk_bf16(float lo, float hi) {
  unsigned r;
  asm("v_cvt_pk_bf16_f32 %0, %1, %2" : "=v"(r) : "v"(lo), "v"(hi));
  return r;
}
// v_permlane32_swap_b32 vdst, vsrc:
//   new vdst = [old vdst lanes 0-31 | old vsrc lanes 0-31]
//   new vsrc = [old vdst lanes 32-63 | old vsrc lanes 32-63]
// Only safe when a and b are DISTINCT values (distinct VGPRs).
__device__ __forceinline__ void swap32(unsigned &a, unsigned &b) {
  asm("v_permlane32_swap_b32 %0, %1" : "+v"(a), "+v"(b));
}
__device__ __forceinline__ f32x16 zero16() {
  f32x16 v;
  #pragma unroll
  for (int e = 0; e < 16; ++e) v[e] = 0.f;
  return v;
}

// ---------------- fp32 -> bf16 conversion (x + 4 weights fused) ----------------
__global__ void cvt_all(const float* __restrict__ x,  const float* __restrict__ wq,
                        const float* __restrict__ wk, const float* __restrict__ wv,
                        const float* __restrict__ wo,
                        unsigned short* __restrict__ xb,  unsigned short* __restrict__ wqb,
                        unsigned short* __restrict__ wkb, unsigned short* __restrict__ wvb,
                        unsigned short* __restrict__ wob)
{
  int i = (blockIdx.x * 256 + threadIdx.x) * 4;
  if (i >= MM * EE + 4 * EE * EE) return;
  const float* s; unsigned short* d; int off;
  if (i < MM * EE) { s = x; d = xb; off = i; }
  else {
    int k = i - MM * EE;
    int w = k >> 20;               // EE*EE = 1<<20
    off = k & (EE * EE - 1);
    s = (w == 0) ? wq : (w == 1) ? wk : (w == 2) ? wv : wo;
    d = (w == 0) ? wqb : (w == 1) ? wkb : (w == 2) ? wvb : wob;
  }
  float4 v = *(const float4*)(s + off);
  union { unsigned short s[4]; uint2 u; } o;
  o.s[0] = f32_bf16(v.x); o.s[1] = f32_bf16(v.y);
  o.s[2] = f32_bf16(v.z); o.s[3] = f32_bf16(v.w);
  *(uint2*)(d + off) = o.u;
}

// ---------------- 128x128 bf16 GEMM (NT: A MxK, W NxK) ----------------
// MODE 0: QKV projection. z=0: Q -> (B,H,L,D), *mask*1/sqrt(D); z=1: K -> (B,H,L,D), *mask;
//         z=2: V^T -> (B,H,D,L), *mask.
// MODE 1: out = A @ W0^T + bias, fp32 row-major.
template<int MODE>
__global__ __launch_bounds__(256, 2)
void gemm128(const unsigned short* __restrict__ A,
             const unsigned short* __restrict__ W0,
             const unsigned short* __restrict__ W1,
             const unsigned short* __restrict__ W2,
             const float* __restrict__ mask,
             const float* __restrict__ bias,
             unsigned short* __restrict__ O0,
             unsigned short* __restrict__ O1,
             unsigned short* __restrict__ O2,
             float* __restrict__ OF)
{
  constexpr int K = EE;
  const int tid = threadIdx.x;
  const int lane = tid & 63;
  const int wid = tid >> 6;
  const int g = lane >> 4, li = lane & 15;
  const int m0 = blockIdx.y * 128;
  const int n0 = blockIdx.x * 128;
  const int z = blockIdx.z;

  const unsigned short* Wp = W0;
  if (MODE == 0) Wp = (z == 0) ? W0 : ((z == 1) ? W1 : W2);

  __shared__ unsigned short As[128 * 64];
  __shared__ unsigned short Bs[128 * 64];

  f32x4 acc[4][4];
  f32x4 zero = {0.f, 0.f, 0.f, 0.f};
  #pragma unroll
  for (int i = 0; i < 4; ++i)
    #pragma unroll
    for (int j = 0; j < 4; ++j) acc[i][j] = zero;

  const int wm = (wid >> 1) * 64;
  const int wn = (wid & 1) * 64;

  for (int kt = 0; kt < K; kt += 64) {
    #pragma unroll
    for (int j = 0; j < 4; ++j) {
      int c = j * 256 + tid;
      int row = c >> 3;
      int lcol = ((c & 7) * 16) ^ ((row & 7) << 4);
      __builtin_amdgcn_global_load_lds(
        (const GPTR void*)((const char*)(A + (size_t)(m0 + row) * K + kt) + lcol),
        (LPTR void*)((char*)As + c * 16), 16, 0, 0);
      __builtin_amdgcn_global_load_lds(
        (const GPTR void*)((const char*)(Wp + (size_t)(n0 + row) * K + kt) + lcol),
        (LPTR void*)((char*)Bs + c * 16), 16, 0, 0);
    }
    __syncthreads();

    #pragma unroll
    for (int kk = 0; kk < 2; ++kk) {
      short8 a[4], b[4];
      const int colb = (kk * 32 + g * 8) * 2;
      #pragma unroll
      for (int i = 0; i < 4; ++i) {
        int ar = wm + i * 16 + li;
        a[i] = *(const short8*)((const char*)As + ar * 128 + (colb ^ ((ar & 7) << 4)));
        int br = wn + i * 16 + li;
        b[i] = *(const short8*)((const char*)Bs + br * 128 + (colb ^ ((br & 7) << 4)));
      }
      #pragma unroll
      for (int i = 0; i < 4; ++i)
        #pragma unroll
        for (int j = 0; j < 4; ++j)
          acc[i][j] = __builtin_amdgcn_mfma_f32_16x16x32_bf16(a[i], b[j], acc[i][j], 0, 0, 0);
    }
    __syncthreads();
  }

  // epilogue. C/D layout: col = li, row = g*4 + r
  if (MODE == 0) {
    if (z == 2) {
      // V^T: (B,H,D,L); 4 consecutive l per (i,j) -> packed 8B store
      #pragma unroll
      for (int i = 0; i < 4; ++i) {
        int mbase = m0 + wm + i * 16 + g * 4;
        int bb2 = mbase >> 11;
        int l0  = mbase & (LL - 1);
        float mk[4];
        #pragma unroll
        for (int r = 0; r < 4; ++r) mk[r] = mask[mbase + r];
        #pragma unroll
        for (int j = 0; j < 4; ++j) {
          int n = n0 + wn + j * 16 + li;
          int h2 = n >> 6, dd2 = n & 63;
          union { unsigned short s[4]; uint2 u; } o;
          #pragma unroll
          for (int r = 0; r < 4; ++r) o.s[r] = f32_bf16(acc[i][j][r] * mk[r]);
          *(uint2*)(O2 + ((size_t)(bb2 * HH + h2) * DD + dd2) * LL + l0) = o.u;
        }
      }
    } else {
      unsigned short* Op = (z == 0) ? O0 : O1;
      const float sc = (z == 0) ? 0.125f : 1.0f;   // 1/sqrt(64) folded into Q
      #pragma unroll
      for (int i = 0; i < 4; ++i) {
        #pragma unroll
        for (int r = 0; r < 4; ++r) {
          int m = m0 + wm + i * 16 + g * 4 + r;
          float mk = mask[m] * sc;
          int bb = m >> 11;
          int l  = m & (LL - 1);
          #pragma unroll
          for (int j = 0; j < 4; ++j) {
            int n = n0 + wn + j * 16 + li;
            int h = n >> 6, d = n & 63;
            size_t off = (((size_t)(bb * HH + h)) * LL + l) * DD + d;
            Op[off] = f32_bf16(acc[i][j][r] * mk);
          }
        }
      }
    }
  } else {
    #pragma unroll
    for (int i = 0; i < 4; ++i) {
      #pragma unroll
      for (int j = 0; j < 4; ++j) {
        int n = n0 + wn + j * 16 + li;
        float bv = bias[n];
        #pragma unroll
        for (int r = 0; r < 4; ++r) {
          int m = m0 + wm + i * 16 + g * 4 + r;
          OF[(size_t)m * EE + n] = acc[i][j][r] + bv;
        }
      }
    }
  }
}

// ---------------- causal flash attention, swapped-operand form ----------------
// Q (B,H,L,D) pre-scaled by 1/sqrt(D), K (B,H,L,D), VT (B,H,D,L); all mask-folded.
// 4 waves x 32 q-rows = QBLK 128, KVBLK 64, dbuf LDS, 1 barrier/tile.
// S^T = mfma(K_frag, Q_frag): lane q = lane&31, kv = (reg&3)+8*(reg>>2)+4*hi (+32 for s1)
// O^T = mfma(VT_frag, P_frag): lane q = lane&31, d  = (reg&3)+8*(reg>>2)+4*hi (+32 for ot1)
__global__ __launch_bounds__(256, 2)
void attn2(const unsigned short* __restrict__ Q,
           const unsigned short* __restrict__ K,
           const unsigned short* __restrict__ VT,
           unsigned short* __restrict__ Y)
{
  const int tid = threadIdx.x, lane = tid & 63, wq = tid >> 6;
  const int l31 = lane & 31, hi = lane >> 5;
  const int qt = (int)gridDim.x - 1 - (int)blockIdx.x;   // heavy blocks first
  const int q0 = qt * 128;
  const int bh = blockIdx.y;
  const int b = bh >> 4, h = bh & (HH - 1);
  const size_t kbase = (size_t)bh * LL * DD;

  __shared__ unsigned short Ks[2][64 * 64];
  __shared__ unsigned short Vs[2][64 * 64];

  const unsigned short* Kg  = K + kbase;
  const unsigned short* VTg = VT + kbase;   // (D,L) within head

  const int qrow = q0 + wq * 32 + l31;
  const int qmin = q0 + wq * 32;

  short8 qf0, qf1, qf2, qf3;
  {
    const unsigned short* Qr = Q + kbase + (size_t)qrow * DD + hi * 8;
    qf0 = *(const short8*)(Qr);
    qf1 = *(const short8*)(Qr + 16);
    qf2 = *(const short8*)(Qr + 32);
    qf3 = *(const short8*)(Qr + 48);
  }

  f32x16 ot0 = zero16(), ot1 = zero16();
  float m = -INFINITY, lsum = 0.f;

  const int nt = (q0 + 128) >> 6;

  auto stage = [&](int buf, int t2) {
    const int kv0s = t2 << 6;
    #pragma unroll
    for (int u = 0; u < 2; ++u) {
      int c = u * 256 + tid;
      int row = c >> 3;
      int cb = (c & 7) * 16;
      int scol = cb ^ ((row & 7) << 4);
      __builtin_amdgcn_global_load_lds(
        (const GPTR void*)((const char*)(Kg + (size_t)(kv0s + row) * DD) + scol),
        (LPTR void*)((char*)Ks[buf] + c * 16), 16, 0, 0);
      __builtin_amdgcn_global_load_lds(
        (const GPTR void*)((const char*)(VTg + (size_t)row * LL + kv0s) + scol),
        (LPTR void*)((char*)Vs[buf] + c * 16), 16, 0, 0);
    }
  };

  stage(0, 0);
  int cur = 0;

  for (int t = 0; t < nt; ++t) {
    __syncthreads();                       // buf[cur] staged (vmcnt drained here)
    if (t + 1 < nt) stage(cur ^ 1, t + 1); // next tile in flight during compute
    const int kv0 = t << 6;

    if (kv0 <= qmin + 31) {                // wave-uniform skip of fully-masked tiles
      const char* Kb_ = (const char*)Ks[cur];
      const char* Vb_ = (const char*)Vs[cur];
      const int cb0 = hi * 16;
      const int r0 = l31, r1 = 32 + l31;
      const int swz = ((l31 & 7) << 4);

      // ---- S^T = K · Q^T ----
      f32x16 s0 = zero16(), s1 = zero16();
      #pragma unroll
      for (int kc = 0; kc < 4; ++kc) {
        int cb = kc * 32 + cb0;
        short8 k0 = *(const short8*)(Kb_ + r0 * 128 + (cb ^ swz));
        short8 k1 = *(const short8*)(Kb_ + r1 * 128 + (cb ^ swz));
        short8 qv = (kc == 0) ? qf0 : (kc == 1) ? qf1 : (kc == 2) ? qf2 : qf3;
        s0 = __builtin_amdgcn_mfma_f32_32x32x16_bf16(k0, qv, s0, 0, 0, 0);
        s1 = __builtin_amdgcn_mfma_f32_32x32x16_bf16(k1, qv, s1, 0, 0, 0);
      }

      // ---- causal mask (only near-diagonal tiles) ----
      if (kv0 + 63 > qmin) {
        #pragma unroll
        for (int rg = 0; rg < 4; ++rg)
          #pragma unroll
          for (int e = 0; e < 4; ++e) {
            int kvg = kv0 + rg * 8 + hi * 4 + e;
            if (kvg > qrow)      s0[rg * 4 + e] = -INFINITY;
            if (kvg + 32 > qrow) s1[rg * 4 + e] = -INFINITY;
          }
      }

      // ---- online softmax: lane-local reduce + one cross-half shfl ----
      float mv = s0[0];
      #pragma unroll
      for (int e = 1; e < 16; ++e) mv = fmaxf(mv, s0[e]);
      #pragma unroll
      for (int e = 0; e < 16; ++e) mv = fmaxf(mv, s1[e]);
      mv = fmaxf(mv, __shfl_xor(mv, 32, 64));
      float mnew = fmaxf(m, mv);
      float al = __expf(m - mnew);
      m = mnew;
      float rs = 0.f;
      #pragma unroll
      for (int e = 0; e < 16; ++e) { s0[e] = __expf(s0[e] - mnew); rs += s0[e]; }
      #pragma unroll
      for (int e = 0; e < 16; ++e) { s1[e] = __expf(s1[e] - mnew); rs += s1[e]; }
      rs += __shfl_xor(rs, 32, 64);
      lsum = lsum * al + rs;
      #pragma unroll
      for (int e = 0; e < 16; ++e) { ot0[e] *= al; ot1[e] *= al; }

      // ---- P fragments: cvt_pk + permlane32_swap (T12) ----
      // a0=(kv 4hi+0,4hi+1) a1=(4hi+2,4hi+3) b0=(8+4hi,9+4hi) b1=(10+4hi,11+4hi)
      // target word w in lane(hi): kv pair (hi*8+2w, hi*8+2w+1)
      // swap32(a0,b0): a0 -> [a0@lo | b0@lo] = word0 ; b0 -> [a0@hi | b0@hi] = word2
      auto mkfrag = [&](const f32x16& sv, int base) -> short8 {
        unsigned a0 = pk_bf16(sv[base + 0], sv[base + 1]);
        unsigned a1 = pk_bf16(sv[base + 2], sv[base + 3]);
        unsigned b0 = pk_bf16(sv[base + 4], sv[base + 5]);
        unsigned b1 = pk_bf16(sv[base + 6], sv[base + 7]);
        swap32(a0, b0);
        swap32(a1, b1);
        union { unsigned u[4]; short8 s; } f;
        f.u[0] = a0; f.u[1] = a1; f.u[2] = b0; f.u[3] = b1;
        return f.s;
      };
      short8 pf0 = mkfrag(s0, 0), pf1 = mkfrag(s0, 8);
      short8 pf2 = mkfrag(s1, 0), pf3 = mkfrag(s1, 8);

      // ---- O^T += V^T · P^T ----
      #pragma unroll
      for (int kc = 0; kc < 4; ++kc) {
        int cb = kc * 32 + cb0;
        short8 v0 = *(const short8*)(Vb_ + r0 * 128 + (cb ^ swz));
        short8 v1 = *(const short8*)(Vb_ + r1 * 128 + (cb ^ swz));
        short8 pv = (kc == 0) ? pf0 : (kc == 1) ? pf1 : (kc == 2) ? pf2 : pf3;
        ot0 = __builtin_amdgcn_mfma_f32_32x32x16_bf16(v0, pv, ot0, 0, 0, 0);
        ot1 = __builtin_amdgcn_mfma_f32_32x32x16_bf16(v1, pv, ot1, 0, 0, 0);
      }
    }
    cur ^= 1;
  }

  // ---- epilogue: Y (B,L,E) bf16, packed 8B stores ----
  float inv = 1.0f / lsum;
  unsigned short* Yr = Y + ((size_t)b * LL + qrow) * EE + h * DD;
  #pragma unroll
  for (int rg = 0; rg < 4; ++rg) {
    union { unsigned short s[4]; uint2 u; } o0, o1;
    #pragma unroll
    for (int e = 0; e < 4; ++e) {
      o0.s[e] = f32_bf16(ot0[rg * 4 + e] * inv);
      o1.s[e] = f32_bf16(ot1[rg * 4 + e] * inv);
    }
    *(uint2*)(Yr + rg * 8 + hi * 4) = o0.u;
    *(uint2*)(Yr + 32 + rg * 8 + hi * 4) = o1.u;
  }
}

// ---------------- launch ----------------
extern "C" void kernel_launch(void* const* d_in, const int* in_sizes, int n_in,
                              void* d_out, int out_size, void* d_ws, size_t ws_size,
                              hipStream_t stream) {
  const float* x    = (const float*)d_in[0];
  const float* mask = (const float*)d_in[1];
  const float* Wq   = (const float*)d_in[2];
  const float* Wk   = (const float*)d_in[3];
  const float* Wv   = (const float*)d_in[4];
  const float* Wo   = (const float*)d_in[5];
  const float* bo   = (const float*)d_in[6];
  float* out = (float*)d_out;

  char* ws = (char*)d_ws;
  unsigned short* xb  = (unsigned short*)(ws);
  unsigned short* wqb = (unsigned short*)(ws + ((size_t)8  << 20));
  unsigned short* wkb = (unsigned short*)(ws + ((size_t)10 << 20));
  unsigned short* wvb = (unsigned short*)(ws + ((size_t)12 << 20));
  unsigned short* wob = (unsigned short*)(ws + ((size_t)14 << 20));
  unsigned short* Qb  = (unsigned short*)(ws + ((size_t)16 << 20));
  unsigned short* Kb  = (unsigned short*)(ws + ((size_t)24 << 20));
  unsigned short* VTb = (unsigned short*)(ws + ((size_t)32 << 20));
  unsigned short* Yb  = (unsigned short*)(ws + ((size_t)40 << 20));

  cvt_all<<<8192, 256, 0, stream>>>(x, Wq, Wk, Wv, Wo, xb, wqb, wkb, wvb, wob);

  gemm128<0><<<dim3(EE / 128, MM / 128, 3), 256, 0, stream>>>(
      xb, wqb, wkb, wvb, mask, nullptr, Qb, Kb, VTb, nullptr);

  attn2<<<dim3(LL / 128, BB * HH), 256, 0, stream>>>(Qb, Kb, VTb, Yb);

  gemm128<1><<<dim3(EE / 128, MM / 128, 1), 256, 0, stream>>>(
      Yb, wob, nullptr, nullptr, nullptr, bo, nullptr, nullptr, nullptr, out);
}

// Round 4
// 121.867 us; speedup vs baseline: 1.9544x; 1.0005x over previous
//
#include <hip/hip_runtime.h>
#include <cstdint>
#include <cstddef>
#include <math.h>

// B=2, L=2048, E=1024, H=16, D=64
#define BB 2
#define LL 2048
#define EE 1024
#define HH 16
#define DD 64
#define MM (BB*LL)

typedef short short8 __attribute__((ext_vector_type(8)));
typedef float f32x4 __attribute__((ext_vector_type(4)));
typedef float f32x16 __attribute__((ext_vector_type(16)));

#define GPTR __attribute__((address_space(1)))
#define LPTR __attribute__((address_space(3)))

__device__ __forceinline__ unsigned short f32_bf16(float f) {
  union { float f; unsigned u; } c; c.f = f;
  c.u += 0x7fffu + ((c.u >> 16) & 1u);
  return (unsigned short)(c.u >> 16);
}

__device__ __forceinline__ unsigned pk_bf16(float lo, float hi) {
  unsigned r;
  asm("v_cvt_pk_bf16_f32 %0, %1, %2" : "=v"(r) : "v"(lo), "v"(hi));
  return r;
}
// v_permlane32_swap_b32 vdst, vsrc:
//   new vdst = [old vdst lanes 0-31 | old vsrc lanes 0-31]
//   new vsrc = [old vdst lanes 32-63 | old vsrc lanes 32-63]
// Operands must be DISTINCT SSA values (else regalloc may alias them).
__device__ __forceinline__ void swap32(unsigned &a, unsigned &b) {
  asm("v_permlane32_swap_b32 %0, %1" : "+v"(a), "+v"(b));
}
__device__ __forceinline__ f32x16 zero16() {
  f32x16 v;
  #pragma unroll
  for (int e = 0; e < 16; ++e) v[e] = 0.f;
  return v;
}

// ---------------- fp32 -> bf16 conversion (x + 4 weights fused) ----------------
__global__ void cvt_all(const float* __restrict__ x,  const float* __restrict__ wq,
                        const float* __restrict__ wk, const float* __restrict__ wv,
                        const float* __restrict__ wo,
                        unsigned short* __restrict__ xb,  unsigned short* __restrict__ wqb,
                        unsigned short* __restrict__ wkb, unsigned short* __restrict__ wvb,
                        unsigned short* __restrict__ wob)
{
  int i = (blockIdx.x * 256 + threadIdx.x) * 4;
  if (i >= MM * EE + 4 * EE * EE) return;
  const float* s; unsigned short* d; int off;
  if (i < MM * EE) { s = x; d = xb; off = i; }
  else {
    int k = i - MM * EE;
    int w = k >> 20;               // EE*EE = 1<<20
    off = k & (EE * EE - 1);
    s = (w == 0) ? wq : (w == 1) ? wk : (w == 2) ? wv : wo;
    d = (w == 0) ? wqb : (w == 1) ? wkb : (w == 2) ? wvb : wob;
  }
  float4 v = *(const float4*)(s + off);
  union { unsigned short s[4]; uint2 u; } o;
  o.s[0] = f32_bf16(v.x); o.s[1] = f32_bf16(v.y);
  o.s[2] = f32_bf16(v.z); o.s[3] = f32_bf16(v.w);
  *(uint2*)(d + off) = o.u;
}

// ---------------- 128x128 bf16 GEMM (NT: A MxK, W NxK) ----------------
// MODE 0: z=0: Q -> (B,H,L,D), *mask*1/sqrt(D); z=1: K -> (B,H,L,D), *mask;
//         z=2: V^T -> (B,H,D,L), *mask.
// MODE 1: out = A @ W0^T + bias, fp32 row-major.
template<int MODE>
__global__ __launch_bounds__(256, 2)
void gemm128(const unsigned short* __restrict__ A,
             const unsigned short* __restrict__ W0,
             const unsigned short* __restrict__ W1,
             const unsigned short* __restrict__ W2,
             const float* __restrict__ mask,
             const float* __restrict__ bias,
             unsigned short* __restrict__ O0,
             unsigned short* __restrict__ O1,
             unsigned short* __restrict__ O2,
             float* __restrict__ OF)
{
  constexpr int K = EE;
  const int tid = threadIdx.x;
  const int lane = tid & 63;
  const int wid = tid >> 6;
  const int g = lane >> 4, li = lane & 15;
  const int m0 = blockIdx.y * 128;
  const int n0 = blockIdx.x * 128;
  const int z = blockIdx.z;

  const unsigned short* Wp = W0;
  if (MODE == 0) Wp = (z == 0) ? W0 : ((z == 1) ? W1 : W2);

  __shared__ unsigned short As[128 * 64];
  __shared__ unsigned short Bs[128 * 64];

  f32x4 acc[4][4];
  f32x4 zero = {0.f, 0.f, 0.f, 0.f};
  #pragma unroll
  for (int i = 0; i < 4; ++i)
    #pragma unroll
    for (int j = 0; j < 4; ++j) acc[i][j] = zero;

  const int wm = (wid >> 1) * 64;
  const int wn = (wid & 1) * 64;

  for (int kt = 0; kt < K; kt += 64) {
    #pragma unroll
    for (int j = 0; j < 4; ++j) {
      int c = j * 256 + tid;
      int row = c >> 3;
      int lcol = ((c & 7) * 16) ^ ((row & 7) << 4);
      __builtin_amdgcn_global_load_lds(
        (const GPTR void*)((const char*)(A + (size_t)(m0 + row) * K + kt) + lcol),
        (LPTR void*)((char*)As + c * 16), 16, 0, 0);
      __builtin_amdgcn_global_load_lds(
        (const GPTR void*)((const char*)(Wp + (size_t)(n0 + row) * K + kt) + lcol),
        (LPTR void*)((char*)Bs + c * 16), 16, 0, 0);
    }
    __syncthreads();

    #pragma unroll
    for (int kk = 0; kk < 2; ++kk) {
      short8 a[4], b[4];
      const int colb = (kk * 32 + g * 8) * 2;
      #pragma unroll
      for (int i = 0; i < 4; ++i) {
        int ar = wm + i * 16 + li;
        a[i] = *(const short8*)((const char*)As + ar * 128 + (colb ^ ((ar & 7) << 4)));
        int br = wn + i * 16 + li;
        b[i] = *(const short8*)((const char*)Bs + br * 128 + (colb ^ ((br & 7) << 4)));
      }
      #pragma unroll
      for (int i = 0; i < 4; ++i)
        #pragma unroll
        for (int j = 0; j < 4; ++j)
          acc[i][j] = __builtin_amdgcn_mfma_f32_16x16x32_bf16(a[i], b[j], acc[i][j], 0, 0, 0);
    }
    __syncthreads();
  }

  // epilogue. C/D layout: col = li, row = g*4 + r
  if (MODE == 0) {
    if (z == 2) {
      #pragma unroll
      for (int i = 0; i < 4; ++i) {
        int mbase = m0 + wm + i * 16 + g * 4;
        int bb2 = mbase >> 11;
        int l0  = mbase & (LL - 1);
        float mk[4];
        #pragma unroll
        for (int r = 0; r < 4; ++r) mk[r] = mask[mbase + r];
        #pragma unroll
        for (int j = 0; j < 4; ++j) {
          int n = n0 + wn + j * 16 + li;
          int h2 = n >> 6, dd2 = n & 63;
          union { unsigned short s[4]; uint2 u; } o;
          #pragma unroll
          for (int r = 0; r < 4; ++r) o.s[r] = f32_bf16(acc[i][j][r] * mk[r]);
          *(uint2*)(O2 + ((size_t)(bb2 * HH + h2) * DD + dd2) * LL + l0) = o.u;
        }
      }
    } else {
      unsigned short* Op = (z == 0) ? O0 : O1;
      const float sc = (z == 0) ? 0.125f : 1.0f;   // 1/sqrt(64) folded into Q
      #pragma unroll
      for (int i = 0; i < 4; ++i) {
        #pragma unroll
        for (int r = 0; r < 4; ++r) {
          int m = m0 + wm + i * 16 + g * 4 + r;
          float mk = mask[m] * sc;
          int bb = m >> 11;
          int l  = m & (LL - 1);
          #pragma unroll
          for (int j = 0; j < 4; ++j) {
            int n = n0 + wn + j * 16 + li;
            int h = n >> 6, d = n & 63;
            size_t off = (((size_t)(bb * HH + h)) * LL + l) * DD + d;
            Op[off] = f32_bf16(acc[i][j][r] * mk);
          }
        }
      }
    }
  } else {
    #pragma unroll
    for (int i = 0; i < 4; ++i) {
      #pragma unroll
      for (int j = 0; j < 4; ++j) {
        int n = n0 + wn + j * 16 + li;
        float bv = bias[n];
        #pragma unroll
        for (int r = 0; r < 4; ++r) {
          int m = m0 + wm + i * 16 + g * 4 + r;
          OF[(size_t)m * EE + n] = acc[i][j][r] + bv;
        }
      }
    }
  }
}

// ---------------- causal flash attention, swapped-operand form ----------------
// QBLK=64 (2 waves x 32 q-rows), KVBLK=64, dbuf LDS, 1 barrier/tile.
// Grid: 1024 flattened blocks, id%8 = bh%8 (XCD-colocated heads), qt descending.
__global__ __launch_bounds__(128, 2)
void attn2(const unsigned short* __restrict__ Q,
           const unsigned short* __restrict__ K,
           const unsigned short* __restrict__ VT,
           unsigned short* __restrict__ Y)
{
  const int tid = threadIdx.x, lane = tid & 63, wq = tid >> 6;
  const int l31 = lane & 31, hi = lane >> 5;

  const int id = blockIdx.x;
  const int bh_lo = id & 7;
  const int r_ = id >> 3;
  const int bh = (r_ & 3) * 8 + bh_lo;      // 4 heads per XCD
  const int qt = 31 - (r_ >> 2);            // heavy q-tiles first
  const int q0 = qt * 64;
  const int b = bh >> 4, h = bh & (HH - 1);
  const size_t kbase = (size_t)bh * LL * DD;

  __shared__ unsigned short Ks[2][64 * 64];
  __shared__ unsigned short Vs[2][64 * 64];

  const unsigned short* Kg  = K + kbase;
  const unsigned short* VTg = VT + kbase;   // (D,L) within head

  const int qrow = q0 + wq * 32 + l31;
  const int qmin = q0 + wq * 32;

  short8 qf0, qf1, qf2, qf3;
  {
    const unsigned short* Qr = Q + kbase + (size_t)qrow * DD + hi * 8;
    qf0 = *(const short8*)(Qr);
    qf1 = *(const short8*)(Qr + 16);
    qf2 = *(const short8*)(Qr + 32);
    qf3 = *(const short8*)(Qr + 48);
  }

  f32x16 ot0 = zero16(), ot1 = zero16();
  float m = -INFINITY, lsum = 0.f;

  const int nt = qt + 1;

  auto stage = [&](int buf, int t2) {
    const int kv0s = t2 << 6;
    #pragma unroll
    for (int u = 0; u < 4; ++u) {
      int c = u * 128 + tid;                // 16B chunk 0..511
      int row = c >> 3;
      int cb = (c & 7) * 16;
      int scol = cb ^ ((row & 7) << 4);
      __builtin_amdgcn_global_load_lds(
        (const GPTR void*)((const char*)(Kg + (size_t)(kv0s + row) * DD) + scol),
        (LPTR void*)((char*)Ks[buf] + c * 16), 16, 0, 0);
      __builtin_amdgcn_global_load_lds(
        (const GPTR void*)((const char*)(VTg + (size_t)row * LL + kv0s) + scol),
        (LPTR void*)((char*)Vs[buf] + c * 16), 16, 0, 0);
    }
  };

  stage(0, 0);
  int cur = 0;

  for (int t = 0; t < nt; ++t) {
    __syncthreads();                       // buf[cur] staged
    if (t + 1 < nt) stage(cur ^ 1, t + 1);
    const int kv0 = t << 6;
    // s1 covers kv0+32..kv0+63; needed iff some lane's qrow >= kv0+32
    const bool need1 = (kv0 + 32 <= qmin + 31);

    const char* Kb_ = (const char*)Ks[cur];
    const char* Vb_ = (const char*)Vs[cur];
    const int cb0 = hi * 16;
    const int r0 = l31, r1 = 32 + l31;
    const int swz = ((l31 & 7) << 4);

    // ---- S^T = K · Q^T ----
    f32x16 s0 = zero16(), s1 = zero16();
    __builtin_amdgcn_s_setprio(1);
    #pragma unroll
    for (int kc = 0; kc < 4; ++kc) {
      int cb = kc * 32 + cb0;
      short8 k0 = *(const short8*)(Kb_ + r0 * 128 + (cb ^ swz));
      short8 qv = (kc == 0) ? qf0 : (kc == 1) ? qf1 : (kc == 2) ? qf2 : qf3;
      s0 = __builtin_amdgcn_mfma_f32_32x32x16_bf16(k0, qv, s0, 0, 0, 0);
      if (need1) {
        short8 k1 = *(const short8*)(Kb_ + r1 * 128 + (cb ^ swz));
        s1 = __builtin_amdgcn_mfma_f32_32x32x16_bf16(k1, qv, s1, 0, 0, 0);
      }
    }
    __builtin_amdgcn_s_setprio(0);

    // ---- causal mask (diagonal tiles only) ----
    if (kv0 + 63 > qmin) {
      #pragma unroll
      for (int rg = 0; rg < 4; ++rg)
        #pragma unroll
        for (int e = 0; e < 4; ++e) {
          int kvg = kv0 + rg * 8 + hi * 4 + e;
          if (kvg > qrow)                s0[rg * 4 + e] = -INFINITY;
          if (need1 && kvg + 32 > qrow)  s1[rg * 4 + e] = -INFINITY;
        }
    }

    // ---- online softmax: tree reduce + one cross-half shfl + defer-max ----
    float red[16];
    #pragma unroll
    for (int e = 0; e < 16; ++e) red[e] = need1 ? fmaxf(s0[e], s1[e]) : s0[e];
    #pragma unroll
    for (int st = 8; st >= 1; st >>= 1)
      #pragma unroll
      for (int e = 0; e < 8; ++e) if (e < st) red[e] = fmaxf(red[e], red[e + st]);
    float mv = red[0];
    mv = fmaxf(mv, __shfl_xor(mv, 32, 64));

    if (!__all(mv <= m + 8.0f)) {          // T13 defer-max
      float mnew = fmaxf(m, mv);
      float al = __expf(m - mnew);
      m = mnew;
      lsum *= al;
      #pragma unroll
      for (int e = 0; e < 16; ++e) { ot0[e] *= al; ot1[e] *= al; }
    }

    float rs;
    {
      float ra[16];
      #pragma unroll
      for (int e = 0; e < 16; ++e) { s0[e] = __expf(s0[e] - m); ra[e] = s0[e]; }
      if (need1) {
        #pragma unroll
        for (int e = 0; e < 16; ++e) { s1[e] = __expf(s1[e] - m); ra[e] += s1[e]; }
      }
      #pragma unroll
      for (int st = 8; st >= 1; st >>= 1)
        #pragma unroll
        for (int e = 0; e < 8; ++e) if (e < st) ra[e] += ra[e + st];
      rs = ra[0];
    }
    rs += __shfl_xor(rs, 32, 64);
    lsum += rs;

    // ---- P fragments: cvt_pk + permlane32_swap (T12) ----
    auto mkfrag = [&](const f32x16& sv, int base) -> short8 {
      unsigned a0 = pk_bf16(sv[base + 0], sv[base + 1]);
      unsigned a1 = pk_bf16(sv[base + 2], sv[base + 3]);
      unsigned b0 = pk_bf16(sv[base + 4], sv[base + 5]);
      unsigned b1 = pk_bf16(sv[base + 6], sv[base + 7]);
      swap32(a0, b0);
      swap32(a1, b1);
      union { unsigned u[4]; short8 s; } f;
      f.u[0] = a0; f.u[1] = a1; f.u[2] = b0; f.u[3] = b1;
      return f.s;
    };
    short8 pf0 = mkfrag(s0, 0), pf1 = mkfrag(s0, 8);

    // ---- O^T += V^T · P^T ----
    __builtin_amdgcn_s_setprio(1);
    #pragma unroll
    for (int kc = 0; kc < 2; ++kc) {
      int cb = kc * 32 + cb0;
      short8 v0 = *(const short8*)(Vb_ + r0 * 128 + (cb ^ swz));
      short8 v1 = *(const short8*)(Vb_ + r1 * 128 + (cb ^ swz));
      short8 pv = (kc == 0) ? pf0 : pf1;
      ot0 = __builtin_amdgcn_mfma_f32_32x32x16_bf16(v0, pv, ot0, 0, 0, 0);
      ot1 = __builtin_amdgcn_mfma_f32_32x32x16_bf16(v1, pv, ot1, 0, 0, 0);
    }
    __builtin_amdgcn_s_setprio(0);
    if (need1) {
      short8 pf2 = mkfrag(s1, 0), pf3 = mkfrag(s1, 8);
      __builtin_amdgcn_s_setprio(1);
      #pragma unroll
      for (int kc = 2; kc < 4; ++kc) {
        int cb = kc * 32 + cb0;
        short8 v0 = *(const short8*)(Vb_ + r0 * 128 + (cb ^ swz));
        short8 v1 = *(const short8*)(Vb_ + r1 * 128 + (cb ^ swz));
        short8 pv = (kc == 2) ? pf2 : pf3;
        ot0 = __builtin_amdgcn_mfma_f32_32x32x16_bf16(v0, pv, ot0, 0, 0, 0);
        ot1 = __builtin_amdgcn_mfma_f32_32x32x16_bf16(v1, pv, ot1, 0, 0, 0);
      }
      __builtin_amdgcn_s_setprio(0);
    }
    cur ^= 1;
  }

  // ---- epilogue: Y (B,L,E) bf16, packed 8B stores ----
  float inv = 1.0f / lsum;
  unsigned short* Yr = Y + ((size_t)b * LL + qrow) * EE + h * DD;
  #pragma unroll
  for (int rg = 0; rg < 4; ++rg) {
    union { unsigned short s[4]; uint2 u; } o0, o1;
    #pragma unroll
    for (int e = 0; e < 4; ++e) {
      o0.s[e] = f32_bf16(ot0[rg * 4 + e] * inv);
      o1.s[e] = f32_bf16(ot1[rg * 4 + e] * inv);
    }
    *(uint2*)(Yr + rg * 8 + hi * 4) = o0.u;
    *(uint2*)(Yr + 32 + rg * 8 + hi * 4) = o1.u;
  }
}

// ---------------- launch ----------------
extern "C" void kernel_launch(void* const* d_in, const int* in_sizes, int n_in,
                              void* d_out, int out_size, void* d_ws, size_t ws_size,
                              hipStream_t stream) {
  const float* x    = (const float*)d_in[0];
  const float* mask = (const float*)d_in[1];
  const float* Wq   = (const float*)d_in[2];
  const float* Wk   = (const float*)d_in[3];
  const float* Wv   = (const float*)d_in[4];
  const float* Wo   = (const float*)d_in[5];
  const float* bo   = (const float*)d_in[6];
  float* out = (float*)d_out;

  char* ws = (char*)d_ws;
  unsigned short* xb  = (unsigned short*)(ws);
  unsigned short* wqb = (unsigned short*)(ws + ((size_t)8  << 20));
  unsigned short* wkb = (unsigned short*)(ws + ((size_t)10 << 20));
  unsigned short* wvb = (unsigned short*)(ws + ((size_t)12 << 20));
  unsigned short* wob = (unsigned short*)(ws + ((size_t)14 << 20));
  unsigned short* Qb  = (unsigned short*)(ws + ((size_t)16 << 20));
  unsigned short* Kb  = (unsigned short*)(ws + ((size_t)24 << 20));
  unsigned short* VTb = (unsigned short*)(ws + ((size_t)32 << 20));
  unsigned short* Yb  = (unsigned short*)(ws + ((size_t)40 << 20));

  cvt_all<<<8192, 256, 0, stream>>>(x, Wq, Wk, Wv, Wo, xb, wqb, wkb, wvb, wob);

  gemm128<0><<<dim3(EE / 128, MM / 128, 3), 256, 0, stream>>>(
      xb, wqb, wkb, wvb, mask, nullptr, Qb, Kb, VTb, nullptr);

  attn2<<<dim3(1024), 128, 0, stream>>>(Qb, Kb, VTb, Yb);

  gemm128<1><<<dim3(EE / 128, MM / 128, 1), 256, 0, stream>>>(
      Yb, wob, nullptr, nullptr, nullptr, bo, nullptr, nullptr, nullptr, out);
}